// Round 13
// baseline (528.419 us; speedup 1.0000x reference)
//
#include <hip/hip_runtime.h>
#include <hip/hip_bf16.h>

#define T_TOK   16384
#define DDIM    2048
#define HDIM    4096
#define NEXP    8
#define BM      256
#define BN      256
#define NKT     64              // 16KB images of K=32 each
#define NKS     32              // K-steps of 64 (2 images)
#define NBAND   (HDIM / BN)     // 16
#define MAX_TILES 72
#define KTB     16384           // image bytes: 256 rows x 32 k x 2B (swizzled)
#define NBLK    (MAX_TILES * NBAND)   // 1152, % 8 == 0
#define PW_BLOCKS 8192                // W-pack: 1024-thread blocks, 8 k/thread
#define PA_BLOCKS (MAX_TILES * NKT)   // 4608

typedef __attribute__((ext_vector_type(4))) float f32x4;
typedef __attribute__((ext_vector_type(8))) __bf16 bf16x8;

// ---- shared int region ----
#define WS_TILE_EXPERT 16
#define WS_TILE_START  (16 + MAX_TILES)
#define WS_TILE_NROWS  (16 + 2*MAX_TILES)
#define WS_ROW_IDS     1024
#define WS_SLOT_POS    18432

// ---- atomic-fallback path offsets ----
#define WS_APACK_OFF   131072ULL
#define WS_APACK_SZ    ((size_t)MAX_TILES * NKT * KTB)              // 75,497,472
#define WS_WB_OFF      (WS_APACK_OFF + WS_APACK_SZ)
#define WS_WB_SZ       ((size_t)NEXP * NBAND * NKT * KTB)           // 134,217,728

// ---- fast2 (y-scratch) path offsets ----
#define WS2_APACK_OFF  262144ULL
#define WS2_WB_OFF     (WS2_APACK_OFF + WS_APACK_SZ)
#define WS2_Y_OFF      (WS2_WB_OFF + WS_WB_SZ)
#define WS2_Y_SZ       ((size_t)T_TOK * HDIM * 2)
#define WS2_NEED       (WS2_Y_OFF + WS2_Y_SZ)                       // 344,195,072

// Image swizzle (verified 0 bank conflicts w/ 16x16 frag reads): 16B-quad q of
// row r at quad (q ^ ((r>>1)&3)) within the row's 64B.

__device__ __forceinline__ void gload16(const void* g, void* l) {
    __builtin_amdgcn_global_load_lds(
        (const __attribute__((address_space(1))) void*)g,
        (__attribute__((address_space(3))) void*)l, 16, 0, 0);
}

// ---- fused W-pack + routing: block 0 routes, blocks 1..PW pack W ----
__global__ __launch_bounds__(1024)
void pack_w_route_kernel(const float* __restrict__ W, const int* __restrict__ topk_ids,
                         int* __restrict__ wsi, int* __restrict__ slot_pos,
                         unsigned char* __restrict__ wb) {
    if (blockIdx.x == 0) {
        // routing (1024-thread LDS-atomic histogram + scatter, R11-verified)
        __shared__ int cnt[NEXP];
        __shared__ int base[NEXP];
        int tid = threadIdx.x;
        if (tid < NEXP) cnt[tid] = 0;
        __syncthreads();
        for (int i = tid; i < T_TOK; i += 1024)
            atomicAdd(&cnt[topk_ids[i]], 1);
        __syncthreads();
        if (tid == 0) {
            int acc = 0, nt = 0;
            for (int e = 0; e < NEXP; ++e) {
                base[e] = acc;
                int c = cnt[e];
                for (int off = 0; off < c; off += BM) {
                    wsi[WS_TILE_EXPERT + nt] = e;
                    wsi[WS_TILE_START + nt]  = acc + off;
                    wsi[WS_TILE_NROWS + nt]  = (c - off < BM) ? (c - off) : BM;
                    nt++;
                }
                acc += c;
            }
            wsi[0] = nt;
        }
        __syncthreads();
        if (tid < NEXP) cnt[tid] = base[tid];
        __syncthreads();
        for (int i = tid; i < T_TOK; i += 1024) {
            int pos = atomicAdd(&cnt[topk_ids[i]], 1);
            wsi[WS_ROW_IDS + pos] = i;
            if (slot_pos) slot_pos[i] = pos;
        }
    } else {
        // W-pack: 8 k-elems per thread, coalesced across n
        long long u = (long long)(blockIdx.x - 1) * 1024 + threadIdx.x;  // 8.4M total
        int n  = (int)(u % HDIM);
        int kb = (int)((u / HDIM) & 255);                   // k-block of 8 (DDIM/8 = 256)
        int e  = (int)(u / ((long long)HDIM * 256));
        const float* src = W + ((size_t)e * DDIM + (size_t)kb * 8) * HDIM + n;
        bf16x8 h;
        #pragma unroll
        for (int j = 0; j < 8; ++j)
            h[j] = (__bf16)src[(size_t)j * HDIM];
        int band = n >> 8;
        int row  = n & 255;
        int kt   = kb >> 2;
        int q    = kb & 3;
        unsigned char* dst = wb + (((size_t)(e * NBAND + band) * NKT + kt) * KTB) + row * 64;
        const int qsw = (row >> 1) & 3;
        *reinterpret_cast<bf16x8*>(dst + ((q ^ qsw) << 4)) = h;
    }
}

// ---- A-pack: gather sorted X rows -> swizzled images (needs routing done) ----
__global__ __launch_bounds__(256)
void pack_a_kernel(const float* __restrict__ X, const int* __restrict__ wsi,
                   unsigned char* __restrict__ apack) {
    const int pa = blockIdx.x;
    const int tile = pa >> 6;
    const int kt   = pa & 63;
    if (tile >= wsi[0]) return;
    const int rstart = wsi[WS_TILE_START + tile];
    const int nrows  = wsi[WS_TILE_NROWS + tile];
    const int r = threadIdx.x;
    unsigned char* dst = apack + ((size_t)tile * NKT + kt) * KTB + r * 64;
    const int qsw = (r >> 1) & 3;
    bf16x8 v0, v1, v2, v3;
    if (r < nrows) {
        int slot = wsi[WS_ROW_IDS + rstart + r];
        const f32x4* p = reinterpret_cast<const f32x4*>(X + (size_t)slot * DDIM + kt * 32);
        f32x4 f[8];
        #pragma unroll
        for (int i = 0; i < 8; ++i) f[i] = p[i];
        #pragma unroll
        for (int j = 0; j < 4; ++j) { v0[j] = (__bf16)f[0][j]; v0[4+j] = (__bf16)f[1][j]; }
        #pragma unroll
        for (int j = 0; j < 4; ++j) { v1[j] = (__bf16)f[2][j]; v1[4+j] = (__bf16)f[3][j]; }
        #pragma unroll
        for (int j = 0; j < 4; ++j) { v2[j] = (__bf16)f[4][j]; v2[4+j] = (__bf16)f[5][j]; }
        #pragma unroll
        for (int j = 0; j < 4; ++j) { v3[j] = (__bf16)f[6][j]; v3[4+j] = (__bf16)f[7][j]; }
    } else {
        #pragma unroll
        for (int j = 0; j < 8; ++j) { v0[j]=(__bf16)0.f; v1[j]=(__bf16)0.f; v2[j]=(__bf16)0.f; v3[j]=(__bf16)0.f; }
    }
    *reinterpret_cast<bf16x8*>(dst + ((0 ^ qsw) << 4)) = v0;
    *reinterpret_cast<bf16x8*>(dst + ((1 ^ qsw) << 4)) = v1;
    *reinterpret_cast<bf16x8*>(dst + ((2 ^ qsw) << 4)) = v2;
    *reinterpret_cast<bf16x8*>(dst + ((3 ^ qsw) << 4)) = v3;
}

// ========== GEMM: 1024 threads / 16 waves / wave-tile 64x64, dbuf 128KB (R12) ==========
#define STAGE_A1(IMG, SB) gload16(agB + (size_t)(IMG) * KTB, smem + (SB) + ((IMG) & 1) * 16384 + ldst)
#define STAGE_B1(IMG, SB) gload16(bgB + (size_t)(IMG) * KTB, smem + (SB) + 32768 + ((IMG) & 1) * 16384 + ldst)
#define LDA1(IMG) do { _Pragma("unroll") for (int mf = 0; mf < 4; ++mf)                    \
    afr[mf] = *reinterpret_cast<const bf16x8*>(smem + cb + (IMG) * 16384 + abase + mf * 1024); } while (0)
#define LDB1(IMG) do { _Pragma("unroll") for (int nf = 0; nf < 4; ++nf)                    \
    bfr[nf] = *reinterpret_cast<const bf16x8*>(smem + cb + 32768 + (IMG) * 16384 + bbase + nf * 1024); } while (0)
#define PHASE_MFMA1() do {                                                                 \
    __builtin_amdgcn_s_setprio(1);                                                         \
    _Pragma("unroll") for (int mf = 0; mf < 4; ++mf)                                       \
        _Pragma("unroll") for (int nf = 0; nf < 4; ++nf)                                   \
            acc[mf][nf] = __builtin_amdgcn_mfma_f32_16x16x32_bf16(afr[mf], bfr[nf], acc[mf][nf], 0, 0, 0); \
    __builtin_amdgcn_s_setprio(0);                                                         \
} while (0)
#define WAIT_LGKM_MFMA_FENCE() do {                                                        \
    __builtin_amdgcn_s_barrier();                                                          \
    asm volatile("s_waitcnt lgkmcnt(0)" ::: "memory");                                     \
    __builtin_amdgcn_sched_barrier(0);                                                     \
} while (0)

#define GEMM_PROLOGUE_AND_MAINLOOP                                                         \
    const int id  = blockIdx.x;                                                            \
    const int swz = (id & 7) * (NBLK / 8) + (id >> 3);                                     \
    const int tile = swz / NBAND;                                                          \
    const int band = swz % NBAND;                                                          \
    if (tile >= wsi[0]) return;                                                            \
    const int e      = wsi[WS_TILE_EXPERT + tile];                                         \
    const int rstart = wsi[WS_TILE_START + tile];                                          \
    const int nrows  = wsi[WS_TILE_NROWS + tile];                                          \
    extern __shared__ unsigned char smem[];                                                \
    const int t    = threadIdx.x;                                                          \
    const int lane = t & 63;                                                               \
    const int wid  = t >> 6;      /* 0..15 */                                              \
    const int wm   = wid >> 2;    /* 0..3: 64-row group */                                 \
    const int wn   = wid & 3;     /* 0..3: 64-col group */                                 \
    const int r16  = lane & 15;                                                            \
    const int c16  = lane >> 4;                                                            \
    const unsigned char* agB = apack + (size_t)tile * NKT * KTB + t * 16;                  \
    const unsigned char* bgB = wb + ((size_t)(e * NBAND + band) * NKT) * KTB + t * 16;     \
    const int ldst = wid * 1024;                                                           \
    const int qswz  = c16 ^ ((r16 >> 1) & 3);                                              \
    const int abase = (wm * 64 + r16) * 64 + (qswz << 4);                                  \
    const int bbase = (wn * 64 + r16) * 64 + (qswz << 4);                                  \
    f32x4 acc[4][4];                                                                       \
    _Pragma("unroll") for (int i = 0; i < 4; ++i)                                          \
        _Pragma("unroll") for (int j = 0; j < 4; ++j)                                      \
            acc[i][j] = (f32x4)(0.0f);                                                     \
    STAGE_A1(0, 0); STAGE_B1(0, 0); STAGE_A1(1, 0); STAGE_B1(1, 0);                        \
    asm volatile("s_waitcnt vmcnt(2)" ::: "memory");  /* even pair landed, odd in flight */\
    __builtin_amdgcn_s_barrier();                                                          \
    __builtin_amdgcn_sched_barrier(0);                                                     \
    _Pragma("unroll 1")                                                                    \
    for (int ks = 0; ks < NKS - 1; ++ks) {                                                 \
        const int cb = (ks & 1) << 16;                                                     \
        const int sb = cb ^ 65536;                                                         \
        bf16x8 afr[4], bfr[4];                                                             \
        /* P0: img-even */                                                                 \
        LDA1(0); LDB1(0);                                                                  \
        STAGE_A1(2 * ks + 2, sb); STAGE_B1(2 * ks + 2, sb);                                \
        asm volatile("s_waitcnt vmcnt(2)" ::: "memory");  /* odd pair landed for P1 */     \
        WAIT_LGKM_MFMA_FENCE();                                                            \
        PHASE_MFMA1();                                                                     \
        __builtin_amdgcn_s_barrier();                                                      \
        /* P1: img-odd */                                                                  \
        LDA1(1); LDB1(1);                                                                  \
        STAGE_A1(2 * ks + 3, sb); STAGE_B1(2 * ks + 3, sb);                                \
        asm volatile("s_waitcnt vmcnt(2)" ::: "memory");  /* next-even pair landed */      \
        WAIT_LGKM_MFMA_FENCE();                                                            \
        PHASE_MFMA1();                                                                     \
        __builtin_amdgcn_s_barrier();                                                      \
    }                                                                                      \
    {   /* tail K-step: no staging */                                                      \
        const int cb = ((NKS - 1) & 1) << 16;                                              \
        bf16x8 afr[4], bfr[4];                                                             \
        LDA1(0); LDB1(0);                                                                  \
        asm volatile("s_waitcnt vmcnt(0)" ::: "memory");  /* drain odd pair */             \
        WAIT_LGKM_MFMA_FENCE();                                                            \
        PHASE_MFMA1();                                                                     \
        __builtin_amdgcn_s_barrier();                                                      \
        LDA1(1); LDB1(1);                                                                  \
        asm volatile("s_waitcnt lgkmcnt(0)" ::: "memory");                                 \
        __builtin_amdgcn_sched_barrier(0);                                                 \
        PHASE_MFMA1();                                                                     \
    }

// ---- fast2: y-scratch epilogue (pure bf16 stores, no atomics) ----
__global__ __launch_bounds__(1024, 4)
void gemm_fast2(const unsigned char* __restrict__ apack,
                const unsigned char* __restrict__ wb,
                const float* __restrict__ topk_weight,
                const int* __restrict__ wsi,
                __hip_bfloat16* __restrict__ yb) {
    GEMM_PROLOGUE_AND_MAINLOOP
    const int col0 = band * BN + wn * 64 + r16;
    #pragma unroll
    for (int mf = 0; mf < 4; ++mf) {
        const int rbase = wm * 64 + mf * 16 + c16 * 4;
        #pragma unroll
        for (int i = 0; i < 4; ++i) {
            int rl = rbase + i;
            if (rl < nrows) {
                int spos = rstart + rl;
                float wt = topk_weight[wsi[WS_ROW_IDS + spos]];
                __hip_bfloat16* yr = yb + (size_t)spos * HDIM + col0;
                #pragma unroll
                for (int nf = 0; nf < 4; ++nf)
                    yr[nf * 16] = (__hip_bfloat16)(acc[mf][nf][i] * wt);
            }
        }
    }
}

// ---- atomic fallback epilogue ----
__global__ __launch_bounds__(1024, 4)
void gemm_fast(const unsigned char* __restrict__ apack,
               const unsigned char* __restrict__ wb,
               const float* __restrict__ topk_weight,
               const int* __restrict__ wsi,
               float* __restrict__ Out) {
    GEMM_PROLOGUE_AND_MAINLOOP
    const int col0 = band * BN + wn * 64 + r16;
    #pragma unroll
    for (int mf = 0; mf < 4; ++mf) {
        const int rbase = wm * 64 + mf * 16 + c16 * 4;
        #pragma unroll
        for (int i = 0; i < 4; ++i) {
            int rl = rbase + i;
            if (rl < nrows) {
                int slot = wsi[WS_ROW_IDS + rstart + rl];
                float wt = topk_weight[slot];
                float* orow = Out + (size_t)(slot >> 1) * HDIM + col0;
                #pragma unroll
                for (int nf = 0; nf < 4; ++nf)
                    atomicAdd(orow + nf * 16, acc[mf][nf][i] * wt);
            }
        }
    }
}

// ---- reduce: out[t] = y[pos(2t)] + y[pos(2t+1)] ----
__global__ __launch_bounds__(512)
void reduce_kernel(const __hip_bfloat16* __restrict__ yb,
                   const int* __restrict__ slot_pos,
                   float* __restrict__ Out) {
    const int tk = blockIdx.x;
    const int c  = threadIdx.x;
    const int p0 = slot_pos[2 * tk];
    const int p1 = slot_pos[2 * tk + 1];
    const bf16x8 a = *reinterpret_cast<const bf16x8*>(yb + (size_t)p0 * HDIM + c * 8);
    const bf16x8 b = *reinterpret_cast<const bf16x8*>(yb + (size_t)p1 * HDIM + c * 8);
    f32x4 o0, o1;
    #pragma unroll
    for (int j = 0; j < 4; ++j) o0[j] = (float)a[j] + (float)b[j];
    #pragma unroll
    for (int j = 0; j < 4; ++j) o1[j] = (float)a[4 + j] + (float)b[4 + j];
    float* orow = Out + (size_t)tk * HDIM + c * 8;
    *reinterpret_cast<f32x4*>(orow)     = o0;
    *reinterpret_cast<f32x4*>(orow + 4) = o1;
}

extern "C" void kernel_launch(void* const* d_in, const int* in_sizes, int n_in,
                              void* d_out, int out_size, void* d_ws, size_t ws_size,
                              hipStream_t stream) {
    const float* X   = (const float*)d_in[0];
    const float* W   = (const float*)d_in[1];
    const float* wgt = (const float*)d_in[2];
    const int*   ids = (const int*)d_in[3];
    float* Out = (float*)d_out;
    int*   wsi = (int*)d_ws;

    if (ws_size >= WS2_NEED) {
        unsigned char* apack = (unsigned char*)d_ws + WS2_APACK_OFF;
        unsigned char* wb    = (unsigned char*)d_ws + WS2_WB_OFF;
        __hip_bfloat16* yb   = (__hip_bfloat16*)((unsigned char*)d_ws + WS2_Y_OFF);
        int* slot_pos        = wsi + WS_SLOT_POS;
        pack_w_route_kernel<<<PW_BLOCKS + 1, 1024, 0, stream>>>(W, ids, wsi, slot_pos, wb);
        pack_a_kernel<<<PA_BLOCKS, 256, 0, stream>>>(X, wsi, apack);
        gemm_fast2<<<NBLK, 1024, 131072, stream>>>(apack, wb, wgt, wsi, yb);
        reduce_kernel<<<T_TOK / 2, 512, 0, stream>>>(yb, slot_pos, Out);
    } else {
        unsigned char* apack = (unsigned char*)d_ws + WS_APACK_OFF;
        unsigned char* wb    = (unsigned char*)d_ws + WS_WB_OFF;
        hipMemsetAsync(d_out, 0, (size_t)out_size * sizeof(float), stream);
        pack_w_route_kernel<<<PW_BLOCKS + 1, 1024, 0, stream>>>(W, ids, wsi, nullptr, wb);
        pack_a_kernel<<<PA_BLOCKS, 256, 0, stream>>>(X, wsi, apack);
        gemm_fast<<<NBLK, 1024, 131072, stream>>>(apack, wb, wgt, wsi, Out);
    }
}

// Round 14
// 499.442 us; speedup vs baseline: 1.0580x; 1.0580x over previous
//
#include <hip/hip_runtime.h>
#include <hip/hip_bf16.h>

#define T_TOK   16384
#define DDIM    2048
#define HDIM    4096
#define NEXP    8
#define BM      256
#define BN      256
#define NKT     64              // 16KB images of K=32 each
#define NKS     32              // K-steps of 64 (2 images)
#define NBAND   (HDIM / BN)     // 16
#define MAX_TILES 72
#define KTB     16384           // image bytes: 256 rows x 32 k x 2B (swizzled)
#define NBLK    (MAX_TILES * NBAND)   // 1152, % 8 == 0
#define PW_BLOCKS 32768               // W-pack: 8 k-elems/thread, 256-thread blocks
#define PA_BLOCKS (MAX_TILES * NKT)   // 4608

typedef __attribute__((ext_vector_type(4))) float f32x4;
typedef __attribute__((ext_vector_type(8))) __bf16 bf16x8;

// ---- shared int region ----
#define WS_TILE_EXPERT 16
#define WS_TILE_START  (16 + MAX_TILES)
#define WS_TILE_NROWS  (16 + 2*MAX_TILES)
#define WS_ROW_IDS     1024
#define WS_SLOT_POS    18432

// ---- atomic-fallback path offsets ----
#define WS_APACK_OFF   131072ULL
#define WS_APACK_SZ    ((size_t)MAX_TILES * NKT * KTB)              // 75,497,472
#define WS_WB_OFF      (WS_APACK_OFF + WS_APACK_SZ)
#define WS_WB_SZ       ((size_t)NEXP * NBAND * NKT * KTB)           // 134,217,728

// ---- fast2 (y-scratch) path offsets ----
#define WS2_APACK_OFF  262144ULL
#define WS2_WB_OFF     (WS2_APACK_OFF + WS_APACK_SZ)
#define WS2_Y_OFF      (WS2_WB_OFF + WS_WB_SZ)
#define WS2_Y_SZ       ((size_t)T_TOK * HDIM * 2)
#define WS2_NEED       (WS2_Y_OFF + WS2_Y_SZ)                       // 344,195,072

// Image swizzle (verified 0 bank conflicts w/ 16x16 frag reads): 16B-quad q of
// row r at quad (q ^ ((r>>1)&3)) within the row's 64B.

__device__ __forceinline__ void gload16(const void* g, void* l) {
    __builtin_amdgcn_global_load_lds(
        (const __attribute__((address_space(1))) void*)g,
        (__attribute__((address_space(3))) void*)l, 16, 0, 0);
}

// ---- routing: 1024-thread LDS-atomic histogram + scatter ----
__global__ __launch_bounds__(1024)
void routing_kernel(const int* __restrict__ topk_ids, int* __restrict__ wsi,
                    int* __restrict__ slot_pos) {
    __shared__ int cnt[NEXP];
    __shared__ int base[NEXP];
    int tid = threadIdx.x;
    if (tid < NEXP) cnt[tid] = 0;
    __syncthreads();
    for (int i = tid; i < T_TOK; i += 1024)
        atomicAdd(&cnt[topk_ids[i]], 1);
    __syncthreads();
    if (tid == 0) {
        int acc = 0, nt = 0;
        for (int e = 0; e < NEXP; ++e) {
            base[e] = acc;
            int c = cnt[e];
            for (int off = 0; off < c; off += BM) {
                wsi[WS_TILE_EXPERT + nt] = e;
                wsi[WS_TILE_START + nt]  = acc + off;
                wsi[WS_TILE_NROWS + nt]  = (c - off < BM) ? (c - off) : BM;
                nt++;
            }
            acc += c;
        }
        wsi[0] = nt;
    }
    __syncthreads();
    if (tid < NEXP) cnt[tid] = base[tid];
    __syncthreads();
    for (int i = tid; i < T_TOK; i += 1024) {
        int pos = atomicAdd(&cnt[topk_ids[i]], 1);
        wsi[WS_ROW_IDS + pos] = i;
        if (slot_pos) slot_pos[i] = pos;
    }
}

// ---- merged pack: blocks [0,PW) pack W (8 k/thread), [PW,PW+PA) gather A ----
__global__ __launch_bounds__(256)
void pack_all_kernel(const float* __restrict__ W, const float* __restrict__ X,
                     const int* __restrict__ wsi,
                     unsigned char* __restrict__ wb, unsigned char* __restrict__ apack) {
    const int bid = blockIdx.x;
    if (bid < PW_BLOCKS) {
        long long u = (long long)bid * 256 + threadIdx.x;   // NEXP*(DDIM/8)*HDIM = 8.4M
        int n  = (int)(u % HDIM);
        int kb = (int)((u / HDIM) & 255);                   // k-block of 8 (DDIM/8 = 256)
        int e  = (int)(u / ((long long)HDIM * 256));
        const float* src = W + ((size_t)e * DDIM + (size_t)kb * 8) * HDIM + n;
        bf16x8 h;
        #pragma unroll
        for (int j = 0; j < 8; ++j)
            h[j] = (__bf16)src[(size_t)j * HDIM];
        int band = n >> 8;
        int row  = n & 255;
        int kt   = kb >> 2;
        int q    = kb & 3;
        unsigned char* dst = wb + (((size_t)(e * NBAND + band) * NKT + kt) * KTB) + row * 64;
        const int qsw = (row >> 1) & 3;
        *reinterpret_cast<bf16x8*>(dst + ((q ^ qsw) << 4)) = h;
    } else {
        const int pa = bid - PW_BLOCKS;
        const int tile = pa >> 6;
        const int kt   = pa & 63;
        if (tile >= wsi[0]) return;
        const int rstart = wsi[WS_TILE_START + tile];
        const int nrows  = wsi[WS_TILE_NROWS + tile];
        const int r = threadIdx.x;
        unsigned char* dst = apack + ((size_t)tile * NKT + kt) * KTB + r * 64;
        const int qsw = (r >> 1) & 3;
        bf16x8 v0, v1, v2, v3;
        if (r < nrows) {
            int slot = wsi[WS_ROW_IDS + rstart + r];
            const f32x4* p = reinterpret_cast<const f32x4*>(X + (size_t)slot * DDIM + kt * 32);
            f32x4 f[8];
            #pragma unroll
            for (int i = 0; i < 8; ++i) f[i] = p[i];
            #pragma unroll
            for (int j = 0; j < 4; ++j) { v0[j] = (__bf16)f[0][j]; v0[4+j] = (__bf16)f[1][j]; }
            #pragma unroll
            for (int j = 0; j < 4; ++j) { v1[j] = (__bf16)f[2][j]; v1[4+j] = (__bf16)f[3][j]; }
            #pragma unroll
            for (int j = 0; j < 4; ++j) { v2[j] = (__bf16)f[4][j]; v2[4+j] = (__bf16)f[5][j]; }
            #pragma unroll
            for (int j = 0; j < 4; ++j) { v3[j] = (__bf16)f[6][j]; v3[4+j] = (__bf16)f[7][j]; }
        } else {
            #pragma unroll
            for (int j = 0; j < 8; ++j) { v0[j]=(__bf16)0.f; v1[j]=(__bf16)0.f; v2[j]=(__bf16)0.f; v3[j]=(__bf16)0.f; }
        }
        *reinterpret_cast<bf16x8*>(dst + ((0 ^ qsw) << 4)) = v0;
        *reinterpret_cast<bf16x8*>(dst + ((1 ^ qsw) << 4)) = v1;
        *reinterpret_cast<bf16x8*>(dst + ((2 ^ qsw) << 4)) = v2;
        *reinterpret_cast<bf16x8*>(dst + ((3 ^ qsw) << 4)) = v3;
    }
}

// ========== GEMM: 1024 threads / 16 waves / wave-tile 64x64, dbuf 128KB ==========
// buffer cb (64KB): A img-even @cb, A img-odd @cb+16K, B img-even @cb+32K, B img-odd @cb+48K
#define STAGE_A1(IMG, SB) gload16(agB + (size_t)(IMG) * KTB, smem + (SB) + ((IMG) & 1) * 16384 + ldst)
#define STAGE_B1(IMG, SB) gload16(bgB + (size_t)(IMG) * KTB, smem + (SB) + 32768 + ((IMG) & 1) * 16384 + ldst)
#define LDA1(IMG) do { _Pragma("unroll") for (int mf = 0; mf < 4; ++mf)                    \
    afr[mf] = *reinterpret_cast<const bf16x8*>(smem + cb + (IMG) * 16384 + abase + mf * 1024); } while (0)
#define LDB1(IMG) do { _Pragma("unroll") for (int nf = 0; nf < 4; ++nf)                    \
    bfr[nf] = *reinterpret_cast<const bf16x8*>(smem + cb + 32768 + (IMG) * 16384 + bbase + nf * 1024); } while (0)
#define PHASE_MFMA1() do {                                                                 \
    __builtin_amdgcn_s_setprio(1);                                                         \
    _Pragma("unroll") for (int mf = 0; mf < 4; ++mf)                                       \
        _Pragma("unroll") for (int nf = 0; nf < 4; ++nf)                                   \
            acc[mf][nf] = __builtin_amdgcn_mfma_f32_16x16x32_bf16(afr[mf], bfr[nf], acc[mf][nf], 0, 0, 0); \
    __builtin_amdgcn_s_setprio(0);                                                         \
} while (0)
#define WAIT_LGKM_MFMA_FENCE() do {                                                        \
    __builtin_amdgcn_s_barrier();                                                          \
    asm volatile("s_waitcnt lgkmcnt(0)" ::: "memory");                                     \
    __builtin_amdgcn_sched_barrier(0);                                                     \
} while (0)

#define GEMM_PROLOGUE_AND_MAINLOOP                                                         \
    const int id  = blockIdx.x;                                                            \
    const int swz = (id & 7) * (NBLK / 8) + (id >> 3);                                     \
    const int tile = swz / NBAND;                                                          \
    const int band = swz % NBAND;                                                          \
    if (tile >= wsi[0]) return;                                                            \
    const int e      = wsi[WS_TILE_EXPERT + tile];                                         \
    const int rstart = wsi[WS_TILE_START + tile];                                          \
    const int nrows  = wsi[WS_TILE_NROWS + tile];                                          \
    extern __shared__ unsigned char smem[];                                                \
    const int t    = threadIdx.x;                                                          \
    const int lane = t & 63;                                                               \
    const int wid  = t >> 6;      /* 0..15 */                                              \
    const int wm   = wid >> 2;    /* 0..3: 64-row group */                                 \
    const int wn   = wid & 3;     /* 0..3: 64-col group */                                 \
    const int r16  = lane & 15;                                                            \
    const int c16  = lane >> 4;                                                            \
    const unsigned char* agB = apack + (size_t)tile * NKT * KTB + t * 16;                  \
    const unsigned char* bgB = wb + ((size_t)(e * NBAND + band) * NKT) * KTB + t * 16;     \
    const int ldst = wid * 1024;                                                           \
    const int qswz  = c16 ^ ((r16 >> 1) & 3);                                              \
    const int abase = (wm * 64 + r16) * 64 + (qswz << 4);                                  \
    const int bbase = (wn * 64 + r16) * 64 + (qswz << 4);                                  \
    f32x4 acc[4][4];                                                                       \
    _Pragma("unroll") for (int i = 0; i < 4; ++i)                                          \
        _Pragma("unroll") for (int j = 0; j < 4; ++j)                                      \
            acc[i][j] = (f32x4)(0.0f);                                                     \
    STAGE_A1(0, 0); STAGE_B1(0, 0); STAGE_A1(1, 0); STAGE_B1(1, 0);                        \
    asm volatile("s_waitcnt vmcnt(2)" ::: "memory");  /* even pair landed, odd in flight */\
    __builtin_amdgcn_s_barrier();                                                          \
    __builtin_amdgcn_sched_barrier(0);                                                     \
    _Pragma("unroll 1")                                                                    \
    for (int ks = 0; ks < NKS - 1; ++ks) {                                                 \
        const int cb = (ks & 1) << 16;                                                     \
        const int sb = cb ^ 65536;                                                         \
        bf16x8 afr[4], bfr[4];                                                             \
        /* P0: img-even */                                                                 \
        LDA1(0); LDB1(0);                                                                  \
        STAGE_A1(2 * ks + 2, sb); STAGE_B1(2 * ks + 2, sb);                                \
        asm volatile("s_waitcnt vmcnt(2)" ::: "memory");  /* odd pair landed for P1 */     \
        WAIT_LGKM_MFMA_FENCE();                                                            \
        PHASE_MFMA1();                                                                     \
        __builtin_amdgcn_s_barrier();                                                      \
        /* P1: img-odd */                                                                  \
        LDA1(1); LDB1(1);                                                                  \
        STAGE_A1(2 * ks + 3, sb); STAGE_B1(2 * ks + 3, sb);                                \
        asm volatile("s_waitcnt vmcnt(2)" ::: "memory");  /* next-even pair landed */      \
        WAIT_LGKM_MFMA_FENCE();                                                            \
        PHASE_MFMA1();                                                                     \
        __builtin_amdgcn_s_barrier();                                                      \
    }                                                                                      \
    {   /* tail K-step: no staging */                                                      \
        const int cb = ((NKS - 1) & 1) << 16;                                              \
        bf16x8 afr[4], bfr[4];                                                             \
        LDA1(0); LDB1(0);                                                                  \
        asm volatile("s_waitcnt vmcnt(0)" ::: "memory");  /* drain odd pair */             \
        WAIT_LGKM_MFMA_FENCE();                                                            \
        PHASE_MFMA1();                                                                     \
        __builtin_amdgcn_s_barrier();                                                      \
        LDA1(1); LDB1(1);                                                                  \
        asm volatile("s_waitcnt lgkmcnt(0)" ::: "memory");                                 \
        __builtin_amdgcn_sched_barrier(0);                                                 \
        PHASE_MFMA1();                                                                     \
    }

// ---- fast2: y-scratch epilogue (pure bf16 stores, no atomics) ----
__global__ __launch_bounds__(1024, 4)
void gemm_fast2(const unsigned char* __restrict__ apack,
                const unsigned char* __restrict__ wb,
                const float* __restrict__ topk_weight,
                const int* __restrict__ wsi,
                __hip_bfloat16* __restrict__ yb) {
    GEMM_PROLOGUE_AND_MAINLOOP
    const int col0 = band * BN + wn * 64 + r16;
    #pragma unroll
    for (int mf = 0; mf < 4; ++mf) {
        const int rbase = wm * 64 + mf * 16 + c16 * 4;
        #pragma unroll
        for (int i = 0; i < 4; ++i) {
            int rl = rbase + i;
            if (rl < nrows) {
                int spos = rstart + rl;
                float wt = topk_weight[wsi[WS_ROW_IDS + spos]];
                __hip_bfloat16* yr = yb + (size_t)spos * HDIM + col0;
                #pragma unroll
                for (int nf = 0; nf < 4; ++nf)
                    yr[nf * 16] = (__hip_bfloat16)(acc[mf][nf][i] * wt);
            }
        }
    }
}

// ---- atomic fallback epilogue ----
__global__ __launch_bounds__(1024, 4)
void gemm_fast(const unsigned char* __restrict__ apack,
               const unsigned char* __restrict__ wb,
               const float* __restrict__ topk_weight,
               const int* __restrict__ wsi,
               float* __restrict__ Out) {
    GEMM_PROLOGUE_AND_MAINLOOP
    const int col0 = band * BN + wn * 64 + r16;
    #pragma unroll
    for (int mf = 0; mf < 4; ++mf) {
        const int rbase = wm * 64 + mf * 16 + c16 * 4;
        #pragma unroll
        for (int i = 0; i < 4; ++i) {
            int rl = rbase + i;
            if (rl < nrows) {
                int slot = wsi[WS_ROW_IDS + rstart + rl];
                float wt = topk_weight[slot];
                float* orow = Out + (size_t)(slot >> 1) * HDIM + col0;
                #pragma unroll
                for (int nf = 0; nf < 4; ++nf)
                    atomicAdd(orow + nf * 16, acc[mf][nf][i] * wt);
            }
        }
    }
}

// ---- reduce: out[t] = y[pos(2t)] + y[pos(2t+1)] ----
__global__ __launch_bounds__(512)
void reduce_kernel(const __hip_bfloat16* __restrict__ yb,
                   const int* __restrict__ slot_pos,
                   float* __restrict__ Out) {
    const int tk = blockIdx.x;
    const int c  = threadIdx.x;
    const int p0 = slot_pos[2 * tk];
    const int p1 = slot_pos[2 * tk + 1];
    const bf16x8 a = *reinterpret_cast<const bf16x8*>(yb + (size_t)p0 * HDIM + c * 8);
    const bf16x8 b = *reinterpret_cast<const bf16x8*>(yb + (size_t)p1 * HDIM + c * 8);
    f32x4 o0, o1;
    #pragma unroll
    for (int j = 0; j < 4; ++j) o0[j] = (float)a[j] + (float)b[j];
    #pragma unroll
    for (int j = 0; j < 4; ++j) o1[j] = (float)a[4 + j] + (float)b[4 + j];
    float* orow = Out + (size_t)tk * HDIM + c * 8;
    *reinterpret_cast<f32x4*>(orow)     = o0;
    *reinterpret_cast<f32x4*>(orow + 4) = o1;
}

extern "C" void kernel_launch(void* const* d_in, const int* in_sizes, int n_in,
                              void* d_out, int out_size, void* d_ws, size_t ws_size,
                              hipStream_t stream) {
    const float* X   = (const float*)d_in[0];
    const float* W   = (const float*)d_in[1];
    const float* wgt = (const float*)d_in[2];
    const int*   ids = (const int*)d_in[3];
    float* Out = (float*)d_out;
    int*   wsi = (int*)d_ws;

    if (ws_size >= WS2_NEED) {
        unsigned char* apack = (unsigned char*)d_ws + WS2_APACK_OFF;
        unsigned char* wb    = (unsigned char*)d_ws + WS2_WB_OFF;
        __hip_bfloat16* yb   = (__hip_bfloat16*)((unsigned char*)d_ws + WS2_Y_OFF);
        int* slot_pos        = wsi + WS_SLOT_POS;
        routing_kernel<<<1, 1024, 0, stream>>>(ids, wsi, slot_pos);
        pack_all_kernel<<<PW_BLOCKS + PA_BLOCKS, 256, 0, stream>>>(W, X, wsi, wb, apack);
        gemm_fast2<<<NBLK, 1024, 131072, stream>>>(apack, wb, wgt, wsi, yb);
        reduce_kernel<<<T_TOK / 2, 512, 0, stream>>>(yb, slot_pos, Out);
    } else {
        unsigned char* apack = (unsigned char*)d_ws + WS_APACK_OFF;
        unsigned char* wb    = (unsigned char*)d_ws + WS_WB_OFF;
        hipMemsetAsync(d_out, 0, (size_t)out_size * sizeof(float), stream);
        routing_kernel<<<1, 1024, 0, stream>>>(ids, wsi, nullptr);
        pack_all_kernel<<<PW_BLOCKS + PA_BLOCKS, 256, 0, stream>>>(W, X, wsi, wb, apack);
        gemm_fast<<<NBLK, 1024, 131072, stream>>>(apack, wb, wgt, wsi, Out);
    }
}